// Round 1
// baseline (9.780 us; speedup 1.0000x reference)
//
#include <hip/hip_runtime.h>
#include <math.h>

#define N_NODES 30
#define DD 768
#define SS 512
#define NPAIRS 435   // 30*29/2

__global__ __launch_bounds__(512) void legal_pair_kernel(
    const float* __restrict__ bert,   // (B, 512, 768) f32
    const float* __restrict__ re_w,   // (1536,) f32
    const float* __restrict__ re_b,   // (1,) f32
    float* __restrict__ out)          // (B*435,) f32
{
    const int b    = blockIdx.x;
    const int tid  = threadIdx.x;
    const int lane = tid & 63;
    const int wave = tid >> 6;

    __shared__ float s_sm[N_NODES];
    __shared__ float t_sm[N_NODES];

    // Preload weights into registers: lane covers float4 slots lane + 64*it
    const float4* w1p = reinterpret_cast<const float4*>(re_w);
    const float4* w2p = reinterpret_cast<const float4*>(re_w + DD);
    float4 w1v[3], w2v[3];
    #pragma unroll
    for (int it = 0; it < 3; ++it) {
        w1v[it] = w1p[lane + 64 * it];
        w2v[it] = w2p[lane + 64 * it];
    }

    const float* Eb = bert + (size_t)b * SS * DD;

    // 8 waves cover 30 rows: n = wave, wave+8, wave+16, wave+24
    for (int n = wave; n < N_NODES; n += 8) {
        const float4* row = reinterpret_cast<const float4*>(Eb + (size_t)n * DD);
        float s = 0.f, t = 0.f;
        #pragma unroll
        for (int it = 0; it < 3; ++it) {
            float4 e = row[lane + 64 * it];
            s += e.x * w1v[it].x + e.y * w1v[it].y + e.z * w1v[it].z + e.w * w1v[it].w;
            t += e.x * w2v[it].x + e.y * w2v[it].y + e.z * w2v[it].z + e.w * w2v[it].w;
        }
        // 64-lane butterfly reduce (both sums)
        #pragma unroll
        for (int off = 32; off > 0; off >>= 1) {
            s += __shfl_xor(s, off, 64);
            t += __shfl_xor(t, off, 64);
        }
        if (lane == 0) { s_sm[n] = s; t_sm[n] = t; }
    }
    __syncthreads();

    const float bias = re_b[0];
    if (tid < NPAIRS) {
        const int p = tid;
        // invert p -> (i, j): cum(i) = i*(59-i)/2 pairs before row i
        int i = (int)((59.0f - sqrtf((float)(3481 - 8 * p))) * 0.5f);
        while (i * (59 - i) / 2 > p) --i;
        while ((i + 1) * (58 - i) / 2 <= p) ++i;
        const int j = p - i * (59 - i) / 2 + i + 1;
        const float x = s_sm[i] + t_sm[j] + bias;
        out[(size_t)b * NPAIRS + p] = 1.0f / (1.0f + expf(-x));
    }
}

extern "C" void kernel_launch(void* const* d_in, const int* in_sizes, int n_in,
                              void* d_out, int out_size, void* d_ws, size_t ws_size,
                              hipStream_t stream) {
    const float* bert = (const float*)d_in[0];
    const float* re_w = (const float*)d_in[1];
    const float* re_b = (const float*)d_in[2];
    float* out = (float*)d_out;

    const int B = in_sizes[0] / (SS * DD);   // 256
    legal_pair_kernel<<<B, 512, 0, stream>>>(bert, re_w, re_b, out);
}